// Round 1
// baseline (514.183 us; speedup 1.0000x reference)
//
#include <hip/hip_runtime.h>
#include <hip/hip_bf16.h>

#define BB 128
#define TT 512
#define EE 128
#define HH 256
#define MM 1024
#define CC 5

typedef _Float16 h2 __attribute__((ext_vector_type(2)));

__device__ inline h2 mkh2(float a, float b) {
    h2 r; r.x = (_Float16)a; r.y = (_Float16)b; return r;
}

__device__ inline float dot2f(h2 a, h2 b, float c) {
#if __has_builtin(__builtin_amdgcn_fdot2)
    return __builtin_amdgcn_fdot2(a, b, c, false);
#else
    return c + (float)a.x * (float)b.x + (float)a.y * (float)b.y;
#endif
}

__device__ inline float fast_tanh(float x) {
    // tanh(x) = 1 - 2/(exp(2x)+1); exact at both saturation ends
    float e = __expf(2.0f * x);
    return 1.0f - 2.0f / (e + 1.0f);
}

// ---------------------------------------------------------------------------
// K1: u[b][t][j] = b_ih[j] + b_hh[j] + dot(emb[x[b][t]], W_ih[j])  (f16 out)
// Only for active steps t >= T - len[b]. Grid: (8 chunks of 64 tokens, B).
// W_ih row j held in 64 half2 registers; emb row staged in LDS as f16.
// ---------------------------------------------------------------------------
__global__ __launch_bounds__(256, 2)
void k_embed(const int* __restrict__ x, const int* __restrict__ lengths,
             const float* __restrict__ emb, const float* __restrict__ W_ih,
             const float* __restrict__ b_ih, const float* __restrict__ b_hh,
             _Float16* __restrict__ u)
{
    const int b = blockIdx.y;
    const int c = blockIdx.x;          // 64-token chunk
    const int len = lengths[b];
    const int t0 = TT - len;
    const int ts = (c * 64 > t0) ? c * 64 : t0;
    const int te = (c + 1) * 64;
    if (ts >= te) return;              // uniform per block: safe early-exit
    const int j = threadIdx.x;         // output channel 0..255

    h2 w[64];                          // W_ih row j as f16 pairs (64 VGPRs)
    const float4* wrow = (const float4*)(W_ih + (size_t)j * EE);
    #pragma unroll
    for (int kk = 0; kk < 32; ++kk) {
        float4 v = wrow[kk];
        w[2 * kk]     = mkh2(v.x, v.y);
        w[2 * kk + 1] = mkh2(v.z, v.w);
    }
    const float bias = b_ih[j] + b_hh[j];

    __shared__ float4 semb[2][16];     // double-buffered emb row (128 f16)

    for (int t = ts; t < te; ++t) {
        const int tok = x[(size_t)b * TT + t];
        if (j < 64) {
            float2 v = ((const float2*)(emb + (size_t)tok * EE))[j];
            ((h2*)semb[t & 1])[j] = mkh2(v.x, v.y);
        }
        __syncthreads();               // 1 barrier/token (double buffer)
        float acc = bias;
        #pragma unroll
        for (int kk = 0; kk < 16; ++kk) {
            float4 ev = semb[t & 1][kk];   // broadcast LDS read
            h2* ep = (h2*)&ev;
            acc = dot2f(w[4 * kk + 0], ep[0], acc);
            acc = dot2f(w[4 * kk + 1], ep[1], acc);
            acc = dot2f(w[4 * kk + 2], ep[2], acc);
            acc = dot2f(w[4 * kk + 3], ep[3], acc);
        }
        u[((size_t)b * TT + t) * HH + j] = (_Float16)acc;
    }
}

// ---------------------------------------------------------------------------
// K2: the serial scan. One workgroup per batch element, 256 threads, thread j
// owns output channel j. W_hh row j in 128 half2 registers; h in 1 KB LDS,
// double-buffered (1 barrier/step). u[t+1] prefetched during the dot.
// __launch_bounds__(256,1): up to 512 VGPRs, 1 wg/CU -> 128 wgs on 128 CUs.
// ---------------------------------------------------------------------------
__global__ __launch_bounds__(256, 1)
void k_rnn(const int* __restrict__ lengths, const float* __restrict__ W_hh,
           const _Float16* __restrict__ u, float* __restrict__ hn)
{
    const int b = blockIdx.x;
    const int j = threadIdx.x;
    const int len = lengths[b];

    h2 w[128];                         // W_hh row j as f16 pairs (128 VGPRs)
    const float4* wrow = (const float4*)(W_hh + (size_t)j * HH);
    #pragma unroll
    for (int kk = 0; kk < 64; ++kk) {
        float4 v = wrow[kk];
        w[2 * kk]     = mkh2(v.x, v.y);
        w[2 * kk + 1] = mkh2(v.z, v.w);
    }

    __shared__ float4 hbuf[2][HH / 8]; // 2 x 256 f16
    if (j < 64) {
        float4 z; z.x = 0.f; z.y = 0.f; z.z = 0.f; z.w = 0.f;
        hbuf[j >> 5][j & 31] = z;
    }
    __syncthreads();

    const _Float16* up = u + ((size_t)b * TT + (TT - len)) * HH + j;
    float hlast = 0.f;
    _Float16 ucur = (len > 0) ? up[0] : (_Float16)0.f;
    int p = 0;
    for (int t = 0; t < len; ++t) {
        float acc = (float)ucur;
        #pragma unroll
        for (int kk = 0; kk < 32; ++kk) {
            float4 hv = hbuf[p][kk];   // wave-uniform broadcast, no conflicts
            h2* hp = (h2*)&hv;
            acc = dot2f(w[4 * kk + 0], hp[0], acc);
            acc = dot2f(w[4 * kk + 1], hp[1], acc);
            acc = dot2f(w[4 * kk + 2], hp[2], acc);
            acc = dot2f(w[4 * kk + 3], hp[3], acc);
        }
        const int tn = (t + 1 < len) ? (t + 1) : t;   // prefetch next u
        ucur = up[(size_t)tn * HH];
        const float hnew = fast_tanh(acc);
        hlast = hnew;
        ((_Float16*)hbuf[p ^ 1])[j] = (_Float16)hnew;
        __syncthreads();               // 1 barrier/step (double buffer)
        p ^= 1;
    }
    hn[(size_t)b * HH + j] = hlast;    // len==0 -> h stays 0, matches ref
}

// ---------------------------------------------------------------------------
// K3: MLP head + log_softmax. One block per batch row.
// h1 = relu(hn@W0^T + b0) [1024]; logits = relu(h1@W1^T + b1) [5]; logsoftmax.
// ---------------------------------------------------------------------------
__global__ __launch_bounds__(256, 2)
void k_head(const float* __restrict__ hn, const float* __restrict__ W0,
            const float* __restrict__ b0, const float* __restrict__ W1,
            const float* __restrict__ b1, float* __restrict__ out)
{
    const int b = blockIdx.x;
    const int tid = threadIdx.x;
    __shared__ float sh[HH];
    __shared__ float sh1[MM];
    __shared__ float sred[CC][4];
    __shared__ float slog[CC];

    sh[tid] = hn[(size_t)b * HH + tid];
    __syncthreads();

    float acc[4];
    #pragma unroll
    for (int i = 0; i < 4; ++i) acc[i] = b0[tid + 256 * i];
    const float4* sh4 = (const float4*)sh;
    for (int k4 = 0; k4 < HH / 4; ++k4) {
        float4 hv = sh4[k4];
        #pragma unroll
        for (int i = 0; i < 4; ++i) {
            float4 wv = ((const float4*)(W0 + (size_t)(tid + 256 * i) * HH))[k4];
            acc[i] += wv.x * hv.x + wv.y * hv.y + wv.z * hv.z + wv.w * hv.w;
        }
    }
    #pragma unroll
    for (int i = 0; i < 4; ++i) sh1[tid + 256 * i] = fmaxf(acc[i], 0.f);
    __syncthreads();

    float pc[CC] = {0.f, 0.f, 0.f, 0.f, 0.f};
    for (int k = tid; k < MM; k += 256) {
        float hv = sh1[k];
        #pragma unroll
        for (int c = 0; c < CC; ++c) pc[c] += W1[(size_t)c * MM + k] * hv;
    }
    const int lane = tid & 63, wid = tid >> 6;
    #pragma unroll
    for (int c = 0; c < CC; ++c) {
        float v = pc[c];
        #pragma unroll
        for (int off = 32; off > 0; off >>= 1) v += __shfl_down(v, off, 64);
        if (lane == 0) sred[c][wid] = v;
    }
    __syncthreads();
    if (tid < CC) {
        float s = sred[tid][0] + sred[tid][1] + sred[tid][2] + sred[tid][3]
                + b1[tid];
        slog[tid] = fmaxf(s, 0.f);     // second relu per reference
    }
    __syncthreads();
    if (tid < CC) {
        float mx = slog[0];
        #pragma unroll
        for (int c = 1; c < CC; ++c) mx = fmaxf(mx, slog[c]);
        float se = 0.f;
        #pragma unroll
        for (int c = 0; c < CC; ++c) se += __expf(slog[c] - mx);
        out[(size_t)b * CC + tid] = slog[tid] - mx - __logf(se);
    }
}

// ---------------------------------------------------------------------------
extern "C" void kernel_launch(void* const* d_in, const int* in_sizes, int n_in,
                              void* d_out, int out_size, void* d_ws, size_t ws_size,
                              hipStream_t stream) {
    const int*   x       = (const int*)d_in[0];
    const int*   lengths = (const int*)d_in[1];
    const float* emb     = (const float*)d_in[2];
    const float* W_ih    = (const float*)d_in[3];
    const float* W_hh    = (const float*)d_in[4];
    const float* b_ih    = (const float*)d_in[5];
    const float* b_hh    = (const float*)d_in[6];
    const float* W0      = (const float*)d_in[7];
    const float* b0      = (const float*)d_in[8];
    const float* W1      = (const float*)d_in[9];
    const float* b1      = (const float*)d_in[10];
    float* out = (float*)d_out;

    // workspace: u (f16, B*T*H = 33.55 MB) then hn (f32, 128 KB)
    _Float16* u  = (_Float16*)d_ws;
    float*    hn = (float*)((char*)d_ws + (size_t)BB * TT * HH * sizeof(_Float16));

    dim3 g1(TT / 64, BB);
    k_embed<<<g1, 256, 0, stream>>>(x, lengths, emb, W_ih, b_ih, b_hh, u);
    k_rnn  <<<BB, 256, 0, stream>>>(lengths, W_hh, u, hn);
    k_head <<<BB, 256, 0, stream>>>(hn, W0, b0, W1, b1, out);
}

// Round 2
// 511.365 us; speedup vs baseline: 1.0055x; 1.0055x over previous
//
#include <hip/hip_runtime.h>
#include <hip/hip_bf16.h>

#define BB 128
#define TT 512
#define EE 128
#define HH 256
#define MM 1024
#define CC 5

typedef _Float16 h2 __attribute__((ext_vector_type(2)));

__device__ inline h2 mkh2(float a, float b) {
    h2 r; r.x = (_Float16)a; r.y = (_Float16)b; return r;
}

__device__ inline float dot2f(h2 a, h2 b, float c) {
#if __has_builtin(__builtin_amdgcn_fdot2)
    return __builtin_amdgcn_fdot2(a, b, c, false);
#else
    return c + (float)a.x * (float)b.x + (float)a.y * (float)b.y;
#endif
}

// Quad butterfly sum via DPP (VALU pipe, no LDS traffic).
// 0xB1 = quad_perm [1,0,3,2] (xor 1), 0x4E = quad_perm [2,3,0,1] (xor 2).
__device__ inline float dpp_add4(float x) {
    int t = __builtin_amdgcn_update_dpp(0, __builtin_bit_cast(int, x), 0xB1, 0xF, 0xF, true);
    x += __builtin_bit_cast(float, t);
    t = __builtin_amdgcn_update_dpp(0, __builtin_bit_cast(int, x), 0x4E, 0xF, 0xF, true);
    x += __builtin_bit_cast(float, t);
    return x;
}

__device__ inline float fast_tanh(float x) {
    float e = __expf(2.0f * x);
    return 1.0f - 2.0f / (e + 1.0f);
}

// ---------------------------------------------------------------------------
// K1: u[b][t][j] = b_ih[j]+b_hh[j] + dot(emb[x[b][t]], W_ih[j])  (f16 out)
// Split-K(4) per token: thread (kc=tid&3, g=tid>>2) computes outputs 4g..4g+3
// over K-chunk kc (32 of 128). DPP quad butterfly reduces; lane kc keeps
// output 4g+kc == tid (u layout unchanged). emb row double-buffered with
// register prefetch of token t+1.
// ---------------------------------------------------------------------------
__global__ __launch_bounds__(256, 4)
void k_embed(const int* __restrict__ x, const int* __restrict__ lengths,
             const float* __restrict__ emb, const float* __restrict__ W_ih,
             const float* __restrict__ b_ih, const float* __restrict__ b_hh,
             _Float16* __restrict__ u)
{
    const int b = blockIdx.y;
    const int c = blockIdx.x;          // 64-token chunk
    const int len = lengths[b];
    const int t0 = TT - len;
    const int ts = (c * 64 > t0) ? c * 64 : t0;
    const int te = (c + 1) * 64;
    if (ts >= te) return;              // uniform per block
    const int tid = threadIdx.x;
    const int kc = tid & 3;
    const int g  = tid >> 2;

    // W_ih rows 4g..4g+3, cols [kc*32, kc*32+32) as f16 pairs: 64 VGPRs
    h2 w[4][16];
    #pragma unroll
    for (int m = 0; m < 4; ++m) {
        const float4* wr = (const float4*)(W_ih + (size_t)(4*g + m) * EE + kc*32);
        #pragma unroll
        for (int q = 0; q < 8; ++q) {
            float4 v = wr[q];
            w[m][2*q]   = mkh2(v.x, v.y);
            w[m][2*q+1] = mkh2(v.z, v.w);
        }
    }
    const float bias = b_ih[tid] + b_hh[tid];

    __shared__ char sebuf[2][256];     // double-buffered emb row (128 f16)

    // prime buffer 0 with token ts
    {
        int tok = x[(size_t)b * TT + ts];
        if (tid < 64) {
            float2 v = ((const float2*)(emb + (size_t)tok * EE))[tid];
            ((h2*)sebuf[0])[tid] = mkh2(v.x, v.y);
        }
    }
    __syncthreads();

    for (int t = ts; t < te; ++t) {
        // prefetch token t+1 into registers (latency hidden under compute)
        float2 ev; ev.x = 0.f; ev.y = 0.f;
        const bool more = (t + 1 < te);
        if (more && tid < 64) {
            int tok2 = x[(size_t)b * TT + t + 1];
            ev = ((const float2*)(emb + (size_t)tok2 * EE))[tid];
        }

        const char* eb = sebuf[(t - ts) & 1];
        float a0 = 0.f, a1 = 0.f, a2 = 0.f, a3 = 0.f;
        #pragma unroll
        for (int i = 0; i < 4; ++i) {
            // addr kc*64 + i*16: banks collide only 2-way (free)
            float4 hv = *(const float4*)(eb + kc*64 + i*16);
            h2* hp = (h2*)&hv;
            #pragma unroll
            for (int z = 0; z < 4; ++z) {
                a0 = dot2f(w[0][4*i+z], hp[z], a0);
                a1 = dot2f(w[1][4*i+z], hp[z], a1);
                a2 = dot2f(w[2][4*i+z], hp[z], a2);
                a3 = dot2f(w[3][4*i+z], hp[z], a3);
            }
        }
        a0 = dpp_add4(a0); a1 = dpp_add4(a1); a2 = dpp_add4(a2); a3 = dpp_add4(a3);
        float v = (kc == 0) ? a0 : (kc == 1) ? a1 : (kc == 2) ? a2 : a3;
        u[((size_t)b * TT + t) * HH + tid] = (_Float16)(v + bias);

        if (more && tid < 64)
            ((h2*)sebuf[(t - ts + 1) & 1])[tid] = mkh2(ev.x, ev.y);
        __syncthreads();
    }
}

// ---------------------------------------------------------------------------
// K2: serial scan, one workgroup per batch element. Split-K(4) + DPP reduce.
// Thread (kc=tid&3, g=tid>>2): outputs 4g..4g+3 over h-chunk [kc*64,kc*64+64).
// h stored f16 in LDS with bank swizzle: logical j at byte
//   P(j) = (j>>6)*128 + ((((j>>3)&7) + 2*(j>>6)) & 7)*16 + (j&7)*2
// so the quad's 4 concurrent b128 reads hit disjoint bank groups.
// 8 ds_read_b128/thread/step (4x less than R1), 4 independent dot chains.
// ---------------------------------------------------------------------------
__global__ __launch_bounds__(256, 1)
void k_rnn(const int* __restrict__ lengths, const float* __restrict__ W_hh,
           const _Float16* __restrict__ u, float* __restrict__ hn)
{
    const int b = blockIdx.x;
    const int tid = threadIdx.x;
    const int kc = tid & 3;
    const int g  = tid >> 2;
    const int len = lengths[b];

    // W_hh rows 4g..4g+3, cols [kc*64, kc*64+64) as f16 pairs: 128 VGPRs
    h2 w[4][32];
    #pragma unroll
    for (int m = 0; m < 4; ++m) {
        const float4* wr = (const float4*)(W_hh + (size_t)(4*g + m) * HH + kc*64);
        #pragma unroll
        for (int q = 0; q < 16; ++q) {
            float4 v = wr[q];
            w[m][2*q]   = mkh2(v.x, v.y);
            w[m][2*q+1] = mkh2(v.z, v.w);
        }
    }

    __shared__ char hbuf[2][512];
    ((float*)hbuf)[tid] = 0.f;         // zero both buffers (256*4B = 1024B)

    // this thread's h_new write slot (logical j = tid), constant across steps
    const int wr_off = (tid >> 6) * 128
                     + (((((tid >> 3) & 7) + 2 * (tid >> 6)) & 7) << 4)
                     + ((tid & 7) << 1);
    // swizzled read offsets: iter i reads h[kc*64 + 8i .. +7]
    int roff[8];
    #pragma unroll
    for (int i = 0; i < 8; ++i)
        roff[i] = kc * 128 + (((i + 2 * kc) & 7) << 4);

    __syncthreads();

    const _Float16* up = u + ((size_t)b * TT + (TT - len)) * HH + tid;
    float hlast = 0.f;
    _Float16 ucur = (len > 0) ? up[0] : (_Float16)0.f;
    int p = 0;
    for (int t = 0; t < len; ++t) {
        const char* hb = hbuf[p];
        float a0 = 0.f, a1 = 0.f, a2 = 0.f, a3 = 0.f;
        #pragma unroll
        for (int i = 0; i < 8; ++i) {
            float4 hv = *(const float4*)(hb + roff[i]);   // conflict-free
            h2* hp = (h2*)&hv;
            #pragma unroll
            for (int z = 0; z < 4; ++z) {
                a0 = dot2f(w[0][4*i+z], hp[z], a0);
                a1 = dot2f(w[1][4*i+z], hp[z], a1);
                a2 = dot2f(w[2][4*i+z], hp[z], a2);
                a3 = dot2f(w[3][4*i+z], hp[z], a3);
            }
        }
        // prefetch next step's u during the reduction
        const int tn = (t + 1 < len) ? (t + 1) : t;
        _Float16 unext = up[(size_t)tn * HH];

        a0 = dpp_add4(a0); a1 = dpp_add4(a1); a2 = dpp_add4(a2); a3 = dpp_add4(a3);
        float v = (kc == 0) ? a0 : (kc == 1) ? a1 : (kc == 2) ? a2 : a3;
        const float hnew = fast_tanh(v + (float)ucur);
        hlast = hnew;
        *(_Float16*)(hbuf[p ^ 1] + wr_off) = (_Float16)hnew;
        ucur = unext;
        __syncthreads();
        p ^= 1;
    }
    hn[(size_t)b * HH + tid] = hlast;
}

// ---------------------------------------------------------------------------
// K3: MLP head + log_softmax. One block per batch row. (unchanged)
// ---------------------------------------------------------------------------
__global__ __launch_bounds__(256, 2)
void k_head(const float* __restrict__ hn, const float* __restrict__ W0,
            const float* __restrict__ b0, const float* __restrict__ W1,
            const float* __restrict__ b1, float* __restrict__ out)
{
    const int b = blockIdx.x;
    const int tid = threadIdx.x;
    __shared__ float sh[HH];
    __shared__ float sh1[MM];
    __shared__ float sred[CC][4];
    __shared__ float slog[CC];

    sh[tid] = hn[(size_t)b * HH + tid];
    __syncthreads();

    float acc[4];
    #pragma unroll
    for (int i = 0; i < 4; ++i) acc[i] = b0[tid + 256 * i];
    const float4* sh4 = (const float4*)sh;
    for (int k4 = 0; k4 < HH / 4; ++k4) {
        float4 hv = sh4[k4];
        #pragma unroll
        for (int i = 0; i < 4; ++i) {
            float4 wv = ((const float4*)(W0 + (size_t)(tid + 256 * i) * HH))[k4];
            acc[i] += wv.x * hv.x + wv.y * hv.y + wv.z * hv.z + wv.w * hv.w;
        }
    }
    #pragma unroll
    for (int i = 0; i < 4; ++i) sh1[tid + 256 * i] = fmaxf(acc[i], 0.f);
    __syncthreads();

    float pc[CC] = {0.f, 0.f, 0.f, 0.f, 0.f};
    for (int k = tid; k < MM; k += 256) {
        float hv = sh1[k];
        #pragma unroll
        for (int c = 0; c < CC; ++c) pc[c] += W1[(size_t)c * MM + k] * hv;
    }
    const int lane = tid & 63, wid = tid >> 6;
    #pragma unroll
    for (int c = 0; c < CC; ++c) {
        float v = pc[c];
        #pragma unroll
        for (int off = 32; off > 0; off >>= 1) v += __shfl_down(v, off, 64);
        if (lane == 0) sred[c][wid] = v;
    }
    __syncthreads();
    if (tid < CC) {
        float s = sred[tid][0] + sred[tid][1] + sred[tid][2] + sred[tid][3]
                + b1[tid];
        slog[tid] = fmaxf(s, 0.f);
    }
    __syncthreads();
    if (tid < CC) {
        float mx = slog[0];
        #pragma unroll
        for (int c = 1; c < CC; ++c) mx = fmaxf(mx, slog[c]);
        float se = 0.f;
        #pragma unroll
        for (int c = 0; c < CC; ++c) se += __expf(slog[c] - mx);
        out[(size_t)b * CC + tid] = slog[tid] - mx - __logf(se);
    }
}

// ---------------------------------------------------------------------------
extern "C" void kernel_launch(void* const* d_in, const int* in_sizes, int n_in,
                              void* d_out, int out_size, void* d_ws, size_t ws_size,
                              hipStream_t stream) {
    const int*   x       = (const int*)d_in[0];
    const int*   lengths = (const int*)d_in[1];
    const float* emb     = (const float*)d_in[2];
    const float* W_ih    = (const float*)d_in[3];
    const float* W_hh    = (const float*)d_in[4];
    const float* b_ih    = (const float*)d_in[5];
    const float* b_hh    = (const float*)d_in[6];
    const float* W0      = (const float*)d_in[7];
    const float* b0      = (const float*)d_in[8];
    const float* W1      = (const float*)d_in[9];
    const float* b1      = (const float*)d_in[10];
    float* out = (float*)d_out;

    _Float16* u  = (_Float16*)d_ws;
    float*    hn = (float*)((char*)d_ws + (size_t)BB * TT * HH * sizeof(_Float16));

    dim3 g1(TT / 64, BB);
    k_embed<<<g1, 256, 0, stream>>>(x, lengths, emb, W_ih, b_ih, b_hh, u);
    k_rnn  <<<BB, 256, 0, stream>>>(lengths, W_hh, u, hn);
    k_head <<<BB, 256, 0, stream>>>(hn, W0, b0, W1, b1, out);
}